// Round 9
// baseline (71.875 us; speedup 1.0000x reference)
//
#include <hip/hip_runtime.h>

#define S_CACHE 32768
#define NQ 1024
#define D 128
#define KVB 32
#define TILES_TOTAL 1056
#define OBLK_BYTES 8192     // per (qg32, split): O^T packed u32 [chunk][32 q]
#define KV_TILE_BYTES 16384 // prepacked K frags (8 KB) + V frags (8 KB)
#define KV_BYTES ((size_t)TILES_TOTAL * KV_TILE_BYTES)  // 17,301,504

typedef float f32x4 __attribute__((ext_vector_type(4)));
typedef short s16x8 __attribute__((ext_vector_type(8)));
typedef int   i32x4 __attribute__((ext_vector_type(4)));

static __device__ __forceinline__ int cvtpk(float lo, float hi) {
  int r;
  asm("v_cvt_pk_bf16_f32 %0, %1, %2" : "=v"(r) : "v"(lo), "v"(hi));
  return r;
}
static __device__ __forceinline__ s16x8 frag4(int a, int b, int c, int d) {
  i32x4 t = {a, b, c, d};
  return __builtin_bit_cast(s16x8, t);
}
static __device__ __forceinline__ float bf2f(unsigned int b) {
  return __uint_as_float(b << 16);
}
// async global->LDS, 16B per lane; lds dest is wave-uniform base + lane*16
static __device__ __forceinline__ void llds16(const unsigned char* g, unsigned char* l) {
  __builtin_amdgcn_global_load_lds(
      (const __attribute__((address_space(1))) unsigned int*)g,
      (__attribute__((address_space(3))) unsigned int*)l, 16, 0, 0);
}

// ---------------------------------------------------------------------------
// Prepack: K/V f32 -> bf16 in the exact MFMA-fragment LDS image order.
// (Proven R5/R6 kernel, unchanged.)
// ---------------------------------------------------------------------------
__global__ __launch_bounds__(256) void mt_prepack(
    const float* __restrict__ Kc, const float* __restrict__ Vc,
    const float* __restrict__ knew, const float* __restrict__ vnew,
    unsigned char* __restrict__ kv)
{
  const int t = blockIdx.x;
  const int t32 = t * KVB;
  const float* Kb = (t32 < S_CACHE) ? Kc + (size_t)t32 * D
                                    : knew + (size_t)(t32 - S_CACHE) * D;
  const float* Vb = (t32 < S_CACHE) ? Vc + (size_t)t32 * D
                                    : vnew + (size_t)(t32 - S_CACHE) * D;
  unsigned char* outb = kv + (size_t)t * KV_TILE_BYTES;
#pragma unroll
  for (int rep = 0; rep < 4; ++rep) {
    const int id = rep * 256 + threadIdx.x;
    const int chunk = id >> 6;   // uniform per wave
    const int l  = id & 63;
    const int g  = l >> 4, qq = l & 15;
    i32x4 outv;
    if (chunk < 8) {
      const int h = chunk >> 2, c = chunk & 3;
      const int krow = 8 * (qq >> 2) + (qq & 3) + 4 * h;
      const float* src = Kb + (size_t)krow * D + 32 * c + 8 * g;
      f32x4 x0 = *(const f32x4*)src;
      f32x4 x1 = *(const f32x4*)(src + 4);
      outv = i32x4{cvtpk(x0[0], x0[1]), cvtpk(x0[2], x0[3]),
                   cvtpk(x1[0], x1[1]), cvtpk(x1[2], x1[3])};
    } else {
      const int dt = chunk - 8;
      float v[8];
#pragma unroll
      for (int i = 0; i < 8; ++i)
        v[i] = Vb[(size_t)(8 * g + i) * D + 16 * dt + qq];
      outv = i32x4{cvtpk(v[0], v[1]), cvtpk(v[2], v[3]),
                   cvtpk(v[4], v[5]), cvtpk(v[6], v[7])};
    }
    *(i32x4*)(outb + (size_t)chunk * 1024 + l * 16) = outv;
  }
}

// ---------------------------------------------------------------------------
// Main: grid 8*KSPLIT (KSPLIT=96 -> 768 = 3 blocks/CU with 48 KB LDS),
// 256 thr = 4 waves x 32 q. XCD co-location: split s = (n&7)+8*(n>>6).
// 3-buffer counted-vmcnt pipeline in the R6-PROVEN ordering: issue happens
// right after the barrier, BEFORE compute, into the buffer whose last read
// was one full barrier earlier (hoist-tolerant). vmcnt(4) per tile, vmcnt(0)
// only at the peeled last tile. sched_barrier(0) pins (rule #18).
// ---------------------------------------------------------------------------
template <int KSPLIT>
__global__ __launch_bounds__(256) void mt_attn_main(
    const float* __restrict__ qp, const unsigned char* __restrict__ kv,
    unsigned char* __restrict__ ws)
{
  __shared__ __align__(16) unsigned char lds[3][KV_TILE_BYTES];  // 48 KB

  const int tid  = threadIdx.x;
  const int lane = tid & 63;
  const int w    = tid >> 6;
  const int g    = lane >> 4;
  const int qq   = lane & 15;

  const int n    = blockIdx.x;
  const int s    = (n & 7) + 8 * (n >> 6);   // split, pinned to XCD s%8
  const int qg   = (n >> 3) & 7;
  const int qg32 = qg * 4 + w;               // 32-q group per wave
  const int t_st = (s * TILES_TOTAL) / KSPLIT;
  const int t_en = ((s + 1) * TILES_TOTAL) / KSPLIT;
  const int T    = t_en - t_st;              // >= 11 for KSPLIT<=96

  // ---- Q fragments FIRST: all Q loads consumed -> vmcnt clean before staging
  const float QSCALE = 0.0883883476483184f * 1.4426950408889634f;  // 1/sqrt(128)*log2(e)
  s16x8 qf[2][4];
#pragma unroll
  for (int u = 0; u < 2; ++u) {
    const float* qrow = qp + (size_t)(qg32 * 32 + u * 16 + qq) * D + 8 * g;
#pragma unroll
    for (int c = 0; c < 4; ++c) {
      f32x4 x0 = *(const f32x4*)(qrow + 32 * c);
      f32x4 x1 = *(const f32x4*)(qrow + 32 * c + 4);
      qf[u][c] = frag4(cvtpk(x0[0] * QSCALE, x0[1] * QSCALE),
                       cvtpk(x0[2] * QSCALE, x0[3] * QSCALE),
                       cvtpk(x1[0] * QSCALE, x1[1] * QSCALE),
                       cvtpk(x1[2] * QSCALE, x1[3] * QSCALE));
    }
  }

  f32x4 oacc[2][8];
#pragma unroll
  for (int u = 0; u < 2; ++u)
#pragma unroll
    for (int dt = 0; dt < 8; ++dt) {
      f32x4 z = {0.f, 0.f, 0.f, 0.f};
      oacc[u][dt] = z;
    }
  float mrun[2] = {-1e30f, -1e30f};
  float lrun[2] = {0.f, 0.f};

  auto stage_issue = [&](int tile, unsigned char* dst) {
    const unsigned char* src =
        kv + (size_t)(t_st + tile) * KV_TILE_BYTES + w * 1024 + lane * 16;
    unsigned char* d = dst + w * 1024;
#pragma unroll
    for (int r = 0; r < 4; ++r)
      llds16(src + r * 4096, d + r * 4096);
  };

  auto compute = [&](int tile, const unsigned char* buf) {
    const int t32 = (t_st + tile) * KVB;
    // ---- QK^T (swapped): lane(g,qq) -> scores for q=qq, keys 8g+n ----
    f32x4 sc[2][2];
#pragma unroll
    for (int u = 0; u < 2; ++u)
#pragma unroll
      for (int h = 0; h < 2; ++h) {
        f32x4 z = {0.f, 0.f, 0.f, 0.f};
        sc[u][h] = z;
      }
    __builtin_amdgcn_s_setprio(1);
#pragma unroll
    for (int h = 0; h < 2; ++h)
#pragma unroll
      for (int c = 0; c < 4; ++c) {
        s16x8 kf = *(const s16x8*)(buf + (size_t)((h * 4 + c) * 64 + lane) * 16);
        sc[0][h] = __builtin_amdgcn_mfma_f32_16x16x32_bf16(kf, qf[0][c], sc[0][h], 0, 0, 0);
        sc[1][h] = __builtin_amdgcn_mfma_f32_16x16x32_bf16(kf, qf[1][c], sc[1][h], 0, 0, 0);
      }
    __builtin_amdgcn_s_setprio(0);
    // ---- softmax (base-2, lane-local rows) ----
    s16x8 pf[2];
#pragma unroll
    for (int u = 0; u < 2; ++u) {
      float sv[8];
#pragma unroll
      for (int h = 0; h < 2; ++h)
#pragma unroll
        for (int r = 0; r < 4; ++r)
          sv[4 * h + r] = sc[u][h][r];
      if (t32 >= S_CACHE) {  // causal mask (uniform branch per tile)
        const int qglob = qg32 * 32 + u * 16 + qq;
#pragma unroll
        for (int nn = 0; nn < 8; ++nn) {
          const int key = t32 + 8 * g + nn;
          if (key - S_CACHE > qglob) sv[nn] = -1e30f;
        }
      }
      float vmax = fmaxf(fmaxf(fmaxf(sv[0], sv[1]), fmaxf(sv[2], sv[3])),
                         fmaxf(fmaxf(sv[4], sv[5]), fmaxf(sv[6], sv[7])));
      vmax = fmaxf(vmax, __shfl_xor(vmax, 16, 64));
      vmax = fmaxf(vmax, __shfl_xor(vmax, 32, 64));
      if (!__all(vmax <= mrun[u] + 8.f)) {  // defer-max
        const float mnew = fmaxf(mrun[u], vmax);
        const float corr = exp2f(mrun[u] - mnew);
        lrun[u] *= corr;
#pragma unroll
        for (int dt = 0; dt < 8; ++dt) oacc[u][dt] *= corr;
        mrun[u] = mnew;
      }
      float p[8], rs = 0.f;
#pragma unroll
      for (int nn = 0; nn < 8; ++nn) {
        p[nn] = exp2f(sv[nn] - mrun[u]);
        rs += p[nn];
      }
      rs += __shfl_xor(rs, 16, 64);
      rs += __shfl_xor(rs, 32, 64);
      lrun[u] += rs;
      pf[u] = frag4(cvtpk(p[0], p[1]), cvtpk(p[2], p[3]),
                    cvtpk(p[4], p[5]), cvtpk(p[6], p[7]));
    }
    // ---- PV (swapped): O^T += V^T @ P^T ----
    __builtin_amdgcn_s_setprio(1);
#pragma unroll
    for (int dt = 0; dt < 8; ++dt) {
      s16x8 vf = *(const s16x8*)(buf + (size_t)(8192 + (dt * 64 + lane) * 16));
      oacc[0][dt] = __builtin_amdgcn_mfma_f32_16x16x32_bf16(vf, pf[0], oacc[0][dt], 0, 0, 0);
      oacc[1][dt] = __builtin_amdgcn_mfma_f32_16x16x32_bf16(vf, pf[1], oacc[1][dt], 0, 0, 0);
    }
    __builtin_amdgcn_s_setprio(0);
  };

  // ---- 3-buffer counted-vmcnt pipeline (R6-proven ordering) ----
  unsigned char* b0 = lds[0];
  unsigned char* b1 = lds[1];
  unsigned char* b2 = lds[2];
  stage_issue(0, b0);
  stage_issue(1, b1);
  for (int t = 0; t < T - 1; ++t) {
    asm volatile("s_waitcnt vmcnt(4)" ::: "memory");  // own tile-t loads landed
    __builtin_amdgcn_sched_barrier(0);
    __builtin_amdgcn_s_barrier();                     // all waves' slices landed
    __builtin_amdgcn_sched_barrier(0);
    if (t + 2 < T) stage_issue(t + 2, b2);            // b2 last read pre-barrier
    compute(t, b0);
    unsigned char* tmp = b0; b0 = b1; b1 = b2; b2 = tmp;
  }
  asm volatile("s_waitcnt vmcnt(0)" ::: "memory");    // peeled last tile
  __builtin_amdgcn_sched_barrier(0);
  __builtin_amdgcn_s_barrier();
  compute(T - 1, b0);

  // ---- partials: packed u32 O^T (full-line stores) + dense m,l ----
  unsigned char* wsp = ws + KV_BYTES;
  unsigned int* pO = (unsigned int*)(wsp + (size_t)(qg32 * KSPLIT + s) * OBLK_BYTES);
  float* m_ws = (float*)(wsp + (size_t)32 * KSPLIT * OBLK_BYTES);
  float* l_ws = m_ws + (size_t)NQ * KSPLIT;
#pragma unroll
  for (int u = 0; u < 2; ++u) {
#pragma unroll
    for (int dt = 0; dt < 8; ++dt)
#pragma unroll
      for (int r2 = 0; r2 < 2; ++r2)
        pO[(8 * dt + 2 * g + r2) * 32 + u * 16 + qq] =
            (unsigned int)cvtpk(oacc[u][dt][2 * r2], oacc[u][dt][2 * r2 + 1]);
    if (g == 0) {
      const int q = qg32 * 32 + u * 16 + qq;
      m_ws[(size_t)q * KSPLIT + s] = mrun[u];
      l_ws[(size_t)q * KSPLIT + s] = lrun[u];
    }
  }
}

// ---------------------------------------------------------------------------
// Combine, templated on SPLITS for full unroll. One thread per (q, dv).
// ---------------------------------------------------------------------------
template <int S>
__global__ __launch_bounds__(256) void mt_attn_combine(
    const unsigned char* __restrict__ ws, float* __restrict__ out)
{
  const int t  = blockIdx.x * 256 + threadIdx.x;  // 131072 total
  const int ql = t & 31;
  const int dv = (t >> 5) & 127;
  const int qg = t >> 12;
  const int q  = qg * 32 + ql;

  const unsigned char* wsp = ws + KV_BYTES;
  const float* m_ws = (const float*)(wsp + (size_t)32 * S * OBLK_BYTES);
  const float* l_ws = m_ws + (size_t)NQ * S;
  const float* mrow = m_ws + (size_t)q * S;
  const float* lrow = l_ws + (size_t)q * S;

  float mg = -1e30f;
#pragma unroll
  for (int s4 = 0; s4 < S / 4; ++s4) {
    f32x4 m4 = *(const f32x4*)(mrow + 4 * s4);
    mg = fmaxf(mg, fmaxf(fmaxf(m4[0], m4[1]), fmaxf(m4[2], m4[3])));
  }
  float L = 0.f;
#pragma unroll
  for (int s4 = 0; s4 < S / 4; ++s4) {
    f32x4 m4 = *(const f32x4*)(mrow + 4 * s4);
    f32x4 l4 = *(const f32x4*)(lrow + 4 * s4);
    L += l4[0] * exp2f(m4[0] - mg) + l4[1] * exp2f(m4[1] - mg) +
         l4[2] * exp2f(m4[2] - mg) + l4[3] * exp2f(m4[3] - mg);
  }
  // packed-O read: dv -> (dt, g, r); word (8dt+2g+(r>>1))*32 + ql, half r&1
  const int dt = dv >> 4, g2 = (dv >> 2) & 3, r = dv & 3;
  const int word = (8 * dt + 2 * g2 + (r >> 1)) * 32 + ql;
  const int sh = (r & 1) * 16;
  const unsigned int* base =
      (const unsigned int*)(wsp + (size_t)qg * S * OBLK_BYTES) + word;
  float acc = 0.f;
#pragma unroll
  for (int s = 0; s < S; ++s) {
    const float wgt = exp2f(mrow[s] - mg);
    acc += wgt * bf2f((base[(size_t)s * (OBLK_BYTES / 4)] >> sh) & 0xffffu);
  }
  out[(size_t)q * D + dv] = acc / L;
}

extern "C" void kernel_launch(void* const* d_in, const int* in_sizes, int n_in,
                              void* d_out, int out_size, void* d_ws, size_t ws_size,
                              hipStream_t stream)
{
  const float* qp = (const float*)d_in[0];
  const float* kp = (const float*)d_in[1];
  const float* vp = (const float*)d_in[2];
  const float* Kc = (const float*)d_in[3];
  const float* Vc = (const float*)d_in[4];
  float* out = (float*)d_out;
  unsigned char* ws = (unsigned char*)d_ws;

  // ws: [0, KV_BYTES) prepacked KV | O partials | m,l dense
  // need(k) = KV_BYTES + k*(32*8192 + 8*1024) bytes
  static const int cands[] = {96, 64, 48, 32};
  int ksplit = 32;
  for (int i = 0; i < 4; ++i) {
    size_t need = KV_BYTES + (size_t)cands[i] * (32 * OBLK_BYTES + 8 * NQ);
    if (need <= ws_size) { ksplit = cands[i]; break; }
  }

  mt_prepack<<<dim3(TILES_TOTAL), dim3(256), 0, stream>>>(Kc, Vc, kp, vp, ws);

  const dim3 cgrid((NQ * D) / 256), cblk(256);
  switch (ksplit) {
    case 96:
      mt_attn_main<96><<<dim3(768), dim3(256), 0, stream>>>(qp, ws, ws);
      mt_attn_combine<96><<<cgrid, cblk, 0, stream>>>(ws, out);
      break;
    case 64:
      mt_attn_main<64><<<dim3(512), dim3(256), 0, stream>>>(qp, ws, ws);
      mt_attn_combine<64><<<cgrid, cblk, 0, stream>>>(ws, out);
      break;
    case 48:
      mt_attn_main<48><<<dim3(384), dim3(256), 0, stream>>>(qp, ws, ws);
      mt_attn_combine<48><<<cgrid, cblk, 0, stream>>>(ws, out);
      break;
    default:
      mt_attn_main<32><<<dim3(256), dim3(256), 0, stream>>>(qp, ws, ws);
      mt_attn_combine<32><<<cgrid, cblk, 0, stream>>>(ws, out);
      break;
  }
}

// Round 10
// 71.819 us; speedup vs baseline: 1.0008x; 1.0008x over previous
//
#include <hip/hip_runtime.h>

#define S_CACHE 32768
#define NQ 1024
#define D 128
#define KVB 32
#define TILES_TOTAL 1056
#define OBLK_BYTES 8192     // per (qg32, split): O^T packed u32 [chunk][32 q]
#define KV_TILE_BYTES 16384 // prepacked K frags (8 KB) + V frags (8 KB)
#define KV_BYTES ((size_t)TILES_TOTAL * KV_TILE_BYTES)  // 17,301,504

typedef float f32x4 __attribute__((ext_vector_type(4)));
typedef short s16x8 __attribute__((ext_vector_type(8)));
typedef int   i32x4 __attribute__((ext_vector_type(4)));

static __device__ __forceinline__ int cvtpk(float lo, float hi) {
  int r;
  asm("v_cvt_pk_bf16_f32 %0, %1, %2" : "=v"(r) : "v"(lo), "v"(hi));
  return r;
}
static __device__ __forceinline__ s16x8 frag4(int a, int b, int c, int d) {
  i32x4 t = {a, b, c, d};
  return __builtin_bit_cast(s16x8, t);
}
static __device__ __forceinline__ float bf2f(unsigned int b) {
  return __uint_as_float(b << 16);
}
// async global->LDS, 16B per lane; lds dest is wave-uniform base + lane*16
static __device__ __forceinline__ void llds16(const unsigned char* g, unsigned char* l) {
  __builtin_amdgcn_global_load_lds(
      (const __attribute__((address_space(1))) unsigned int*)g,
      (__attribute__((address_space(3))) unsigned int*)l, 16, 0, 0);
}

// ---------------------------------------------------------------------------
// Prepack: K/V f32 -> bf16 in the exact MFMA-fragment LDS image order.
// (Proven R5-R8 kernel, unchanged.)
// ---------------------------------------------------------------------------
__global__ __launch_bounds__(256) void mt_prepack(
    const float* __restrict__ Kc, const float* __restrict__ Vc,
    const float* __restrict__ knew, const float* __restrict__ vnew,
    unsigned char* __restrict__ kv)
{
  const int t = blockIdx.x;
  const int t32 = t * KVB;
  const float* Kb = (t32 < S_CACHE) ? Kc + (size_t)t32 * D
                                    : knew + (size_t)(t32 - S_CACHE) * D;
  const float* Vb = (t32 < S_CACHE) ? Vc + (size_t)t32 * D
                                    : vnew + (size_t)(t32 - S_CACHE) * D;
  unsigned char* outb = kv + (size_t)t * KV_TILE_BYTES;
#pragma unroll
  for (int rep = 0; rep < 4; ++rep) {
    const int id = rep * 256 + threadIdx.x;
    const int chunk = id >> 6;   // uniform per wave
    const int l  = id & 63;
    const int g  = l >> 4, qq = l & 15;
    i32x4 outv;
    if (chunk < 8) {
      const int h = chunk >> 2, c = chunk & 3;
      const int krow = 8 * (qq >> 2) + (qq & 3) + 4 * h;
      const float* src = Kb + (size_t)krow * D + 32 * c + 8 * g;
      f32x4 x0 = *(const f32x4*)src;
      f32x4 x1 = *(const f32x4*)(src + 4);
      outv = i32x4{cvtpk(x0[0], x0[1]), cvtpk(x0[2], x0[3]),
                   cvtpk(x1[0], x1[1]), cvtpk(x1[2], x1[3])};
    } else {
      const int dt = chunk - 8;
      float v[8];
#pragma unroll
      for (int i = 0; i < 8; ++i)
        v[i] = Vb[(size_t)(8 * g + i) * D + 16 * dt + qq];
      outv = i32x4{cvtpk(v[0], v[1]), cvtpk(v[2], v[3]),
                   cvtpk(v[4], v[5]), cvtpk(v[6], v[7])};
    }
    *(i32x4*)(outb + (size_t)chunk * 1024 + l * 16) = outv;
  }
}

// ---------------------------------------------------------------------------
// Main: grid 8*KSPLIT, 256 thr = 4 waves x 32 q. XCD co-location:
// split s = (n&7)+8*(n>>6) pins s's 8 q-blocks to XCD s%8 (R4: FETCH -85%).
//
// Software-pipelined softmax (T15 mechanism): iteration t runs QK^T(t) then
// softmax+PV(t-1) -- independent, so MFMA(t) hides the softmax VALU/shfl
// chain(t-1). K double-buffered, V triple-buffered (K[t] and V[t-1] both
// live). Sync is the R5-PROVEN pattern verbatim: plain __syncthreads per
// tile, stage-issue right after the barrier into a buffer last read one
// full barrier interval ago. TILES compile-time -> full unroll, static
// sc ping-pong (rule #20). Deferred l-reduction: lrun per-lane, one
// cross-lane butterfly in the epilogue (removes 4 shfl/tile).
// ---------------------------------------------------------------------------
template <int KSPLIT>
__global__ __launch_bounds__(256) void mt_attn_main(
    const float* __restrict__ qp, const unsigned char* __restrict__ kv,
    unsigned char* __restrict__ ws)
{
  constexpr int TILES = TILES_TOTAL / KSPLIT;
  static_assert(TILES * KSPLIT == TILES_TOTAL, "KSPLIT must divide 1056");
  static_assert(TILES >= 2, "pipeline needs >=2 tiles");
  __shared__ __align__(16) unsigned char kbuf[2][8192];  // K frags
  __shared__ __align__(16) unsigned char vbuf[3][8192];  // V frags (40 KB total)

  const int tid  = threadIdx.x;
  const int lane = tid & 63;
  const int w    = tid >> 6;
  const int g    = lane >> 4;
  const int qq   = lane & 15;

  const int n    = blockIdx.x;
  const int s    = (n & 7) + 8 * (n >> 6);   // split, pinned to XCD s%8
  const int qg   = (n >> 3) & 7;
  const int qg32 = qg * 4 + w;               // 32-q group per wave
  const int t_st = s * TILES;

  // ---- Q fragments (B-operand): lane holds Q[q][32c+8g+i], scaled ----
  const float QSCALE = 0.0883883476483184f * 1.4426950408889634f;  // 1/sqrt(128)*log2(e)
  s16x8 qf[2][4];
#pragma unroll
  for (int u = 0; u < 2; ++u) {
    const float* qrow = qp + (size_t)(qg32 * 32 + u * 16 + qq) * D + 8 * g;
#pragma unroll
    for (int c = 0; c < 4; ++c) {
      f32x4 x0 = *(const f32x4*)(qrow + 32 * c);
      f32x4 x1 = *(const f32x4*)(qrow + 32 * c + 4);
      qf[u][c] = frag4(cvtpk(x0[0] * QSCALE, x0[1] * QSCALE),
                       cvtpk(x0[2] * QSCALE, x0[3] * QSCALE),
                       cvtpk(x1[0] * QSCALE, x1[1] * QSCALE),
                       cvtpk(x1[2] * QSCALE, x1[3] * QSCALE));
    }
  }

  f32x4 oacc[2][8];
#pragma unroll
  for (int u = 0; u < 2; ++u)
#pragma unroll
    for (int dt = 0; dt < 8; ++dt) {
      f32x4 z = {0.f, 0.f, 0.f, 0.f};
      oacc[u][dt] = z;
    }
  float mrun[2] = {-1e30f, -1e30f};
  float lrun[2] = {0.f, 0.f};

  const unsigned char* kvb =
      kv + (size_t)t_st * KV_TILE_BYTES + w * 1024 + lane * 16;

  auto issueK = [&](int tile, int b) {
    const unsigned char* src = kvb + (size_t)tile * KV_TILE_BYTES;
    unsigned char* dst = &kbuf[b][w * 1024];
    llds16(src, dst);
    llds16(src + 4096, dst + 4096);
  };
  auto issueV = [&](int tile, int b) {
    const unsigned char* src = kvb + (size_t)tile * KV_TILE_BYTES + 8192;
    unsigned char* dst = &vbuf[b][w * 1024];
    llds16(src, dst);
    llds16(src + 4096, dst + 4096);
  };

  auto qkt = [&](const unsigned char* kb, f32x4 (&sc)[2][2]) {
#pragma unroll
    for (int u = 0; u < 2; ++u)
#pragma unroll
      for (int h = 0; h < 2; ++h) {
        f32x4 z = {0.f, 0.f, 0.f, 0.f};
        sc[u][h] = z;
      }
#pragma unroll
    for (int h = 0; h < 2; ++h)
#pragma unroll
      for (int c = 0; c < 4; ++c) {
        s16x8 kf = *(const s16x8*)(kb + (size_t)((h * 4 + c) * 64 + lane) * 16);
        sc[0][h] = __builtin_amdgcn_mfma_f32_16x16x32_bf16(kf, qf[0][c], sc[0][h], 0, 0, 0);
        sc[1][h] = __builtin_amdgcn_mfma_f32_16x16x32_bf16(kf, qf[1][c], sc[1][h], 0, 0, 0);
      }
  };

  auto smaxpv = [&](int tile, f32x4 (&sc)[2][2], const unsigned char* vb) {
    const int t32 = (t_st + tile) * KVB;
    s16x8 pf[2];
#pragma unroll
    for (int u = 0; u < 2; ++u) {
      float sv[8];
#pragma unroll
      for (int h = 0; h < 2; ++h)
#pragma unroll
        for (int r = 0; r < 4; ++r)
          sv[4 * h + r] = sc[u][h][r];
      if (t32 >= S_CACHE) {  // causal mask (uniform branch per tile)
        const int qglob = qg32 * 32 + u * 16 + qq;
#pragma unroll
        for (int nn = 0; nn < 8; ++nn) {
          const int key = t32 + 8 * g + nn;
          if (key - S_CACHE > qglob) sv[nn] = -1e30f;
        }
      }
      float vmax = fmaxf(fmaxf(fmaxf(sv[0], sv[1]), fmaxf(sv[2], sv[3])),
                         fmaxf(fmaxf(sv[4], sv[5]), fmaxf(sv[6], sv[7])));
      vmax = fmaxf(vmax, __shfl_xor(vmax, 16, 64));
      vmax = fmaxf(vmax, __shfl_xor(vmax, 32, 64));
      if (!__all(vmax <= mrun[u] + 8.f)) {  // defer-max
        const float mnew = fmaxf(mrun[u], vmax);
        const float corr = exp2f(mrun[u] - mnew);
        lrun[u] *= corr;
#pragma unroll
        for (int dt = 0; dt < 8; ++dt) oacc[u][dt] *= corr;
        mrun[u] = mnew;
      }
      float p[8], rs = 0.f;
#pragma unroll
      for (int nn = 0; nn < 8; ++nn) {
        p[nn] = exp2f(sv[nn] - mrun[u]);
        rs += p[nn];
      }
      lrun[u] += rs;  // per-lane partial; cross-lane butterfly in epilogue
      pf[u] = frag4(cvtpk(p[0], p[1]), cvtpk(p[2], p[3]),
                    cvtpk(p[4], p[5]), cvtpk(p[6], p[7]));
    }
#pragma unroll
    for (int dt = 0; dt < 8; ++dt) {
      s16x8 vf = *(const s16x8*)(vb + (size_t)(dt * 64 + lane) * 16);
      oacc[0][dt] = __builtin_amdgcn_mfma_f32_16x16x32_bf16(vf, pf[0], oacc[0][dt], 0, 0, 0);
      oacc[1][dt] = __builtin_amdgcn_mfma_f32_16x16x32_bf16(vf, pf[1], oacc[1][dt], 0, 0, 0);
    }
  };

  // ---- pipelined loop: QK^T(t) overlaps softmax+PV(t-1) ----
  f32x4 scbuf[2][2][2];  // [parity][u][h], parity is compile-time (unrolled)
  issueK(0, 0);
  issueV(0, 0);
#pragma unroll
  for (int t = 0; t < TILES; ++t) {
    __syncthreads();  // tile-t loads landed (drain); prior-buf reads done
    if (t + 1 < TILES) {
      issueK(t + 1, (t + 1) & 1);   // kbuf last read at iter t-1 (pre-barrier)
      issueV(t + 1, (t + 1) % 3);   // vbuf held V[t-2], read iter t-1
    }
    qkt(kbuf[t & 1], scbuf[t & 1]);
    if (t > 0) smaxpv(t - 1, scbuf[(t - 1) & 1], vbuf[(t - 1) % 3]);
  }
  smaxpv(TILES - 1, scbuf[(TILES - 1) & 1], vbuf[(TILES - 1) % 3]);

  // ---- epilogue: cross-lane l reduction (butterfly over g groups) ----
#pragma unroll
  for (int u = 0; u < 2; ++u) {
    lrun[u] += __shfl_xor(lrun[u], 16, 64);
    lrun[u] += __shfl_xor(lrun[u], 32, 64);
  }

  // ---- partials: packed u32 O^T (full-line stores) + dense m,l ----
  unsigned char* wsp = ws + KV_BYTES;
  unsigned int* pO = (unsigned int*)(wsp + (size_t)(qg32 * KSPLIT + s) * OBLK_BYTES);
  float* m_ws = (float*)(wsp + (size_t)32 * KSPLIT * OBLK_BYTES);
  float* l_ws = m_ws + (size_t)NQ * KSPLIT;
#pragma unroll
  for (int u = 0; u < 2; ++u) {
#pragma unroll
    for (int dt = 0; dt < 8; ++dt)
#pragma unroll
      for (int r2 = 0; r2 < 2; ++r2)
        pO[(8 * dt + 2 * g + r2) * 32 + u * 16 + qq] =
            (unsigned int)cvtpk(oacc[u][dt][2 * r2], oacc[u][dt][2 * r2 + 1]);
    if (g == 0) {
      const int q = qg32 * 32 + u * 16 + qq;
      m_ws[(size_t)q * KSPLIT + s] = mrun[u];
      l_ws[(size_t)q * KSPLIT + s] = lrun[u];
    }
  }
}

// ---------------------------------------------------------------------------
// Combine, templated on SPLITS for full unroll. One thread per (q, dv).
// ---------------------------------------------------------------------------
template <int S>
__global__ __launch_bounds__(256) void mt_attn_combine(
    const unsigned char* __restrict__ ws, float* __restrict__ out)
{
  const int t  = blockIdx.x * 256 + threadIdx.x;  // 131072 total
  const int ql = t & 31;
  const int dv = (t >> 5) & 127;
  const int qg = t >> 12;
  const int q  = qg * 32 + ql;

  const unsigned char* wsp = ws + KV_BYTES;
  const float* m_ws = (const float*)(wsp + (size_t)32 * S * OBLK_BYTES);
  const float* l_ws = m_ws + (size_t)NQ * S;
  const float* mrow = m_ws + (size_t)q * S;
  const float* lrow = l_ws + (size_t)q * S;

  float mg = -1e30f;
#pragma unroll
  for (int s4 = 0; s4 < S / 4; ++s4) {
    f32x4 m4 = *(const f32x4*)(mrow + 4 * s4);
    mg = fmaxf(mg, fmaxf(fmaxf(m4[0], m4[1]), fmaxf(m4[2], m4[3])));
  }
  float L = 0.f;
#pragma unroll
  for (int s4 = 0; s4 < S / 4; ++s4) {
    f32x4 m4 = *(const f32x4*)(mrow + 4 * s4);
    f32x4 l4 = *(const f32x4*)(lrow + 4 * s4);
    L += l4[0] * exp2f(m4[0] - mg) + l4[1] * exp2f(m4[1] - mg) +
         l4[2] * exp2f(m4[2] - mg) + l4[3] * exp2f(m4[3] - mg);
  }
  // packed-O read: dv -> (dt, g, r); word (8dt+2g+(r>>1))*32 + ql, half r&1
  const int dt = dv >> 4, g2 = (dv >> 2) & 3, r = dv & 3;
  const int word = (8 * dt + 2 * g2 + (r >> 1)) * 32 + ql;
  const int sh = (r & 1) * 16;
  const unsigned int* base =
      (const unsigned int*)(wsp + (size_t)qg * S * OBLK_BYTES) + word;
  float acc = 0.f;
#pragma unroll
  for (int s = 0; s < S; ++s) {
    const float wgt = exp2f(mrow[s] - mg);
    acc += wgt * bf2f((base[(size_t)s * (OBLK_BYTES / 4)] >> sh) & 0xffffu);
  }
  out[(size_t)q * D + dv] = acc / L;
}

extern "C" void kernel_launch(void* const* d_in, const int* in_sizes, int n_in,
                              void* d_out, int out_size, void* d_ws, size_t ws_size,
                              hipStream_t stream)
{
  const float* qp = (const float*)d_in[0];
  const float* kp = (const float*)d_in[1];
  const float* vp = (const float*)d_in[2];
  const float* Kc = (const float*)d_in[3];
  const float* Vc = (const float*)d_in[4];
  float* out = (float*)d_out;
  unsigned char* ws = (unsigned char*)d_ws;

  // ws: [0, KV_BYTES) prepacked KV | O partials | m,l dense
  // need(k) = KV_BYTES + k*(32*8192 + 8*1024)
  static const int cands[] = {96, 48, 32};
  int ksplit = 32;
  for (int i = 0; i < 3; ++i) {
    size_t need = KV_BYTES + (size_t)cands[i] * (32 * OBLK_BYTES + 8 * NQ);
    if (need <= ws_size) { ksplit = cands[i]; break; }
  }

  mt_prepack<<<dim3(TILES_TOTAL), dim3(256), 0, stream>>>(Kc, Vc, kp, vp, ws);

  const dim3 cgrid((NQ * D) / 256), cblk(256);
  switch (ksplit) {
    case 96:
      mt_attn_main<96><<<dim3(768), dim3(256), 0, stream>>>(qp, ws, ws);
      mt_attn_combine<96><<<cgrid, cblk, 0, stream>>>(ws, out);
      break;
    case 48:
      mt_attn_main<48><<<dim3(384), dim3(256), 0, stream>>>(qp, ws, ws);
      mt_attn_combine<48><<<cgrid, cblk, 0, stream>>>(ws, out);
      break;
    default:
      mt_attn_main<32><<<dim3(256), dim3(256), 0, stream>>>(qp, ws, ws);
      mt_attn_combine<32><<<cgrid, cblk, 0, stream>>>(ws, out);
      break;
  }
}

// Round 12
// 66.471 us; speedup vs baseline: 1.0813x; 1.0805x over previous
//
#include <hip/hip_runtime.h>

#define S_CACHE 32768
#define NQ 1024
#define D 128
#define KVB 32
#define TILES_TOTAL 1056
#define OBLK_BYTES 8192     // per (qg32, split): O^T packed u32 [chunk][32 q]
#define KV_TILE_BYTES 16384 // prepacked K frags (8 KB) + V frags (8 KB)
#define KV_BYTES ((size_t)TILES_TOTAL * KV_TILE_BYTES)  // 17,301,504

typedef float f32x4 __attribute__((ext_vector_type(4)));
typedef short s16x8 __attribute__((ext_vector_type(8)));
typedef int   i32x4 __attribute__((ext_vector_type(4)));

static __device__ __forceinline__ int cvtpk(float lo, float hi) {
  int r;
  asm("v_cvt_pk_bf16_f32 %0, %1, %2" : "=v"(r) : "v"(lo), "v"(hi));
  return r;
}
static __device__ __forceinline__ s16x8 frag4(int a, int b, int c, int d) {
  i32x4 t = {a, b, c, d};
  return __builtin_bit_cast(s16x8, t);
}
static __device__ __forceinline__ float bf2f(unsigned int b) {
  return __uint_as_float(b << 16);
}

// ---------------------------------------------------------------------------
// Prepack: K/V f32 -> bf16 in the exact MFMA-fragment image order.
// (Proven R5-R10 kernel, unchanged.)
// ---------------------------------------------------------------------------
__global__ __launch_bounds__(256) void mt_prepack(
    const float* __restrict__ Kc, const float* __restrict__ Vc,
    const float* __restrict__ knew, const float* __restrict__ vnew,
    unsigned char* __restrict__ kv)
{
  const int t = blockIdx.x;
  const int t32 = t * KVB;
  const float* Kb = (t32 < S_CACHE) ? Kc + (size_t)t32 * D
                                    : knew + (size_t)(t32 - S_CACHE) * D;
  const float* Vb = (t32 < S_CACHE) ? Vc + (size_t)t32 * D
                                    : vnew + (size_t)(t32 - S_CACHE) * D;
  unsigned char* outb = kv + (size_t)t * KV_TILE_BYTES;
#pragma unroll
  for (int rep = 0; rep < 4; ++rep) {
    const int id = rep * 256 + threadIdx.x;
    const int chunk = id >> 6;   // uniform per wave
    const int l  = id & 63;
    const int g  = l >> 4, qq = l & 15;
    i32x4 outv;
    if (chunk < 8) {
      const int h = chunk >> 2, c = chunk & 3;
      const int krow = 8 * (qq >> 2) + (qq & 3) + 4 * h;
      const float* src = Kb + (size_t)krow * D + 32 * c + 8 * g;
      f32x4 x0 = *(const f32x4*)src;
      f32x4 x1 = *(const f32x4*)(src + 4);
      outv = i32x4{cvtpk(x0[0], x0[1]), cvtpk(x0[2], x0[3]),
                   cvtpk(x1[0], x1[1]), cvtpk(x1[2], x1[3])};
    } else {
      const int dt = chunk - 8;
      float v[8];
#pragma unroll
      for (int i = 0; i < 8; ++i)
        v[i] = Vb[(size_t)(8 * g + i) * D + 16 * dt + qq];
      outv = i32x4{cvtpk(v[0], v[1]), cvtpk(v[2], v[3]),
                   cvtpk(v[4], v[5]), cvtpk(v[6], v[7])};
    }
    *(i32x4*)(outb + (size_t)chunk * 1024 + l * 16) = outv;
  }
}

// ---------------------------------------------------------------------------
// Main: REGISTER-DIRECT staging (R10) + R9-PROVEN softmax numerics (bisect).
// grid 8*KSPLIT x 256 thr (4 independent waves). XCD co-location:
// s=(n&7)+8*(n>>6) pins split s's readers to XCD s%8.
// Per tile per wave: 8x dwordx4 V loads + 8x K prefetch(t+1) into VGPRs
// (prepacked image is wave-linear, perfectly coalesced) -> 32 MFMA.
// No LDS, no __syncthreads; raw s_barrier only bounds wave drift for L1.
// Softmax: defer-max online (fmax tree + 2 shfl + __all guard + rescale),
// per-lane l accumulation, epilogue butterfly -- byte-for-byte R9.
// ---------------------------------------------------------------------------
template <int KSPLIT>
__global__ __launch_bounds__(256, 2) void mt_attn_main(
    const float* __restrict__ qp, const unsigned char* __restrict__ kv,
    unsigned char* __restrict__ ws)
{
  constexpr int TILES = TILES_TOTAL / KSPLIT;
  static_assert(TILES * KSPLIT == TILES_TOTAL, "KSPLIT must divide 1056");

  const int tid  = threadIdx.x;
  const int lane = tid & 63;
  const int w    = tid >> 6;
  const int g    = lane >> 4;
  const int qq   = lane & 15;

  const int n    = blockIdx.x;
  const int s    = (n & 7) + 8 * (n >> 6);   // split, pinned to XCD s%8
  const int qg   = (n >> 3) & 7;
  const int qg32 = qg * 4 + w;               // 32-q group per wave
  const int t_st = s * TILES;

  // ---- Q fragments (B-operand): lane holds Q[q][32c+8g+i], scaled ----
  const float QSCALE = 0.0883883476483184f * 1.4426950408889634f;  // 1/sqrt(128)*log2(e)
  s16x8 qf[2][4];
#pragma unroll
  for (int u = 0; u < 2; ++u) {
    const float* qrow = qp + (size_t)(qg32 * 32 + u * 16 + qq) * D + 8 * g;
#pragma unroll
    for (int c = 0; c < 4; ++c) {
      f32x4 x0 = *(const f32x4*)(qrow + 32 * c);
      f32x4 x1 = *(const f32x4*)(qrow + 32 * c + 4);
      qf[u][c] = frag4(cvtpk(x0[0] * QSCALE, x0[1] * QSCALE),
                       cvtpk(x0[2] * QSCALE, x0[3] * QSCALE),
                       cvtpk(x1[0] * QSCALE, x1[1] * QSCALE),
                       cvtpk(x1[2] * QSCALE, x1[3] * QSCALE));
    }
  }

  f32x4 oacc[2][8];
#pragma unroll
  for (int u = 0; u < 2; ++u)
#pragma unroll
    for (int dt = 0; dt < 8; ++dt) {
      f32x4 z = {0.f, 0.f, 0.f, 0.f};
      oacc[u][dt] = z;
    }
  float mrun[2] = {-1e30f, -1e30f};
  float lrun[2] = {0.f, 0.f};

  // wave-local fragment base: chunk c of tile t at +t*16K + c*1024 + lane*16
  const unsigned char* kvb = kv + (size_t)t_st * KV_TILE_BYTES + lane * 16;

  i32x4 kk[2][8];  // K fragments, double-buffered (t&1 static under unroll)
  i32x4 vv[8];     // V fragments, per-tile

  // preload K(0)
#pragma unroll
  for (int c = 0; c < 8; ++c)
    kk[0][c] = *(const i32x4*)(kvb + c * 1024);

#pragma unroll
  for (int t = 0; t < TILES; ++t) {
    const unsigned char* tb = kvb + (size_t)t * KV_TILE_BYTES;
    __builtin_amdgcn_s_barrier();  // drift throttle only (no data dep, no drain)

    // issue V(t) loads; consumed after QK^T+softmax (latency hidden)
#pragma unroll
    for (int c = 0; c < 8; ++c)
      vv[c] = *(const i32x4*)(tb + 8192 + c * 1024);

    // ---- QK^T (swapped): lane(g,qq) -> scores for q=qq, keys 8g+nn ----
    f32x4 sc[2][2];
#pragma unroll
    for (int u = 0; u < 2; ++u)
#pragma unroll
      for (int h = 0; h < 2; ++h) {
        f32x4 z = {0.f, 0.f, 0.f, 0.f};
        sc[u][h] = z;
      }
#pragma unroll
    for (int h = 0; h < 2; ++h)
#pragma unroll
      for (int c = 0; c < 4; ++c) {
        s16x8 kf = __builtin_bit_cast(s16x8, kk[t & 1][h * 4 + c]);
        sc[0][h] = __builtin_amdgcn_mfma_f32_16x16x32_bf16(kf, qf[0][c], sc[0][h], 0, 0, 0);
        sc[1][h] = __builtin_amdgcn_mfma_f32_16x16x32_bf16(kf, qf[1][c], sc[1][h], 0, 0, 0);
      }

    // prefetch K(t+1) into the other buffer
    if (t + 1 < TILES) {
#pragma unroll
      for (int c = 0; c < 8; ++c)
        kk[(t + 1) & 1][c] = *(const i32x4*)(tb + KV_TILE_BYTES + c * 1024);
    }

    // ---- softmax (R9-proven: defer-max, base-2, lane-local rows) ----
    const int t32 = (t_st + t) * KVB;
    s16x8 pf[2];
#pragma unroll
    for (int u = 0; u < 2; ++u) {
      float sv[8];
#pragma unroll
      for (int h = 0; h < 2; ++h)
#pragma unroll
        for (int r = 0; r < 4; ++r)
          sv[4 * h + r] = sc[u][h][r];
      if (t32 >= S_CACHE) {  // causal mask (wave-uniform branch per tile)
        const int qglob = qg32 * 32 + u * 16 + qq;
#pragma unroll
        for (int nn = 0; nn < 8; ++nn) {
          const int key = t32 + 8 * g + nn;
          if (key - S_CACHE > qglob) sv[nn] = -1e30f;
        }
      }
      float vmax = fmaxf(fmaxf(fmaxf(sv[0], sv[1]), fmaxf(sv[2], sv[3])),
                         fmaxf(fmaxf(sv[4], sv[5]), fmaxf(sv[6], sv[7])));
      vmax = fmaxf(vmax, __shfl_xor(vmax, 16, 64));
      vmax = fmaxf(vmax, __shfl_xor(vmax, 32, 64));
      if (!__all(vmax <= mrun[u] + 8.f)) {  // defer-max
        const float mnew = fmaxf(mrun[u], vmax);
        const float corr = exp2f(mrun[u] - mnew);
        lrun[u] *= corr;
#pragma unroll
        for (int dt = 0; dt < 8; ++dt) oacc[u][dt] *= corr;
        mrun[u] = mnew;
      }
      float p[8], rs = 0.f;
#pragma unroll
      for (int nn = 0; nn < 8; ++nn) {
        p[nn] = exp2f(sv[nn] - mrun[u]);
        rs += p[nn];
      }
      lrun[u] += rs;  // per-lane partial; butterfly in epilogue (R9-proven)
      pf[u] = frag4(cvtpk(p[0], p[1]), cvtpk(p[2], p[3]),
                    cvtpk(p[4], p[5]), cvtpk(p[6], p[7]));
    }

    // ---- PV (swapped): O^T += V^T @ P^T ----
#pragma unroll
    for (int dt = 0; dt < 8; ++dt) {
      s16x8 vf = __builtin_bit_cast(s16x8, vv[dt]);
      oacc[0][dt] = __builtin_amdgcn_mfma_f32_16x16x32_bf16(vf, pf[0], oacc[0][dt], 0, 0, 0);
      oacc[1][dt] = __builtin_amdgcn_mfma_f32_16x16x32_bf16(vf, pf[1], oacc[1][dt], 0, 0, 0);
    }
  }

  // ---- epilogue: cross-lane l reduction over the 4 g-groups ----
#pragma unroll
  for (int u = 0; u < 2; ++u) {
    lrun[u] += __shfl_xor(lrun[u], 16, 64);
    lrun[u] += __shfl_xor(lrun[u], 32, 64);
  }

  // ---- partials: packed u32 O^T (full-line stores) + dense m,l ----
  unsigned char* wsp = ws + KV_BYTES;
  unsigned int* pO = (unsigned int*)(wsp + (size_t)(qg32 * KSPLIT + s) * OBLK_BYTES);
  float* m_ws = (float*)(wsp + (size_t)32 * KSPLIT * OBLK_BYTES);
  float* l_ws = m_ws + (size_t)NQ * KSPLIT;
#pragma unroll
  for (int u = 0; u < 2; ++u) {
#pragma unroll
    for (int dt = 0; dt < 8; ++dt)
#pragma unroll
      for (int r2 = 0; r2 < 2; ++r2)
        pO[(8 * dt + 2 * g + r2) * 32 + u * 16 + qq] =
            (unsigned int)cvtpk(oacc[u][dt][2 * r2], oacc[u][dt][2 * r2 + 1]);
    if (g == 0) {
      const int q = qg32 * 32 + u * 16 + qq;
      m_ws[(size_t)q * KSPLIT + s] = mrun[u];
      l_ws[(size_t)q * KSPLIT + s] = lrun[u];
    }
  }
}

// ---------------------------------------------------------------------------
// Combine (R9-proven, with m). One thread per (q, dv), full unroll.
// ---------------------------------------------------------------------------
template <int S>
__global__ __launch_bounds__(256) void mt_attn_combine(
    const unsigned char* __restrict__ ws, float* __restrict__ out)
{
  const int t  = blockIdx.x * 256 + threadIdx.x;  // 131072 total
  const int ql = t & 31;
  const int dv = (t >> 5) & 127;
  const int qg = t >> 12;
  const int q  = qg * 32 + ql;

  const unsigned char* wsp = ws + KV_BYTES;
  const float* m_ws = (const float*)(wsp + (size_t)32 * S * OBLK_BYTES);
  const float* l_ws = m_ws + (size_t)NQ * S;
  const float* mrow = m_ws + (size_t)q * S;
  const float* lrow = l_ws + (size_t)q * S;

  float mg = -1e30f;
#pragma unroll
  for (int s4 = 0; s4 < S / 4; ++s4) {
    f32x4 m4 = *(const f32x4*)(mrow + 4 * s4);
    mg = fmaxf(mg, fmaxf(fmaxf(m4[0], m4[1]), fmaxf(m4[2], m4[3])));
  }
  float L = 0.f;
#pragma unroll
  for (int s4 = 0; s4 < S / 4; ++s4) {
    f32x4 m4 = *(const f32x4*)(mrow + 4 * s4);
    f32x4 l4 = *(const f32x4*)(lrow + 4 * s4);
    L += l4[0] * exp2f(m4[0] - mg) + l4[1] * exp2f(m4[1] - mg) +
         l4[2] * exp2f(m4[2] - mg) + l4[3] * exp2f(m4[3] - mg);
  }
  // packed-O read: dv -> (dt, g, r); word (8dt+2g+(r>>1))*32 + ql, half r&1
  const int dt = dv >> 4, g2 = (dv >> 2) & 3, r = dv & 3;
  const int word = (8 * dt + 2 * g2 + (r >> 1)) * 32 + ql;
  const int sh = (r & 1) * 16;
  const unsigned int* base =
      (const unsigned int*)(wsp + (size_t)qg * S * OBLK_BYTES) + word;
  float acc = 0.f;
#pragma unroll
  for (int s = 0; s < S; ++s) {
    const float wgt = exp2f(mrow[s] - mg);
    acc += wgt * bf2f((base[(size_t)s * (OBLK_BYTES / 4)] >> sh) & 0xffffu);
  }
  out[(size_t)q * D + dv] = acc / L;
}

extern "C" void kernel_launch(void* const* d_in, const int* in_sizes, int n_in,
                              void* d_out, int out_size, void* d_ws, size_t ws_size,
                              hipStream_t stream)
{
  const float* qp = (const float*)d_in[0];
  const float* kp = (const float*)d_in[1];
  const float* vp = (const float*)d_in[2];
  const float* Kc = (const float*)d_in[3];
  const float* Vc = (const float*)d_in[4];
  float* out = (float*)d_out;
  unsigned char* ws = (unsigned char*)d_ws;

  // ws: [0, KV_BYTES) prepacked KV | O partials (32*K*8KB) | m,l (2*NQ*K*4)
  static const int cands[] = {96, 48, 32};
  int ksplit = 32;
  for (int i = 0; i < 3; ++i) {
    size_t need = KV_BYTES + (size_t)cands[i] * (32 * OBLK_BYTES + 8 * NQ);
    if (need <= ws_size) { ksplit = cands[i]; break; }
  }

  mt_prepack<<<dim3(TILES_TOTAL), dim3(256), 0, stream>>>(Kc, Vc, kp, vp, ws);

  const dim3 cgrid((NQ * D) / 256), cblk(256);
  switch (ksplit) {
    case 96:
      mt_attn_main<96><<<dim3(768), dim3(256), 0, stream>>>(qp, ws, ws);
      mt_attn_combine<96><<<cgrid, cblk, 0, stream>>>(ws, out);
      break;
    case 48:
      mt_attn_main<48><<<dim3(384), dim3(256), 0, stream>>>(qp, ws, ws);
      mt_attn_combine<48><<<cgrid, cblk, 0, stream>>>(ws, out);
      break;
    default:
      mt_attn_main<32><<<dim3(256), dim3(256), 0, stream>>>(qp, ws, ws);
      mt_attn_combine<32><<<cgrid, cblk, 0, stream>>>(ws, out);
      break;
  }
}

// Round 14
// 62.567 us; speedup vs baseline: 1.1488x; 1.0624x over previous
//
#include <hip/hip_runtime.h>

#define S_CACHE 32768
#define NQ 1024
#define D 128
#define KVB 32
#define TILES_TOTAL 1056
#define OBLK_BYTES 8192     // per (qg32, split): O^T packed u32 [chunk][32 q]
#define KV_TILE_BYTES 16384 // prepacked K frags (8 KB) + V frags (8 KB)
#define KV_BYTES ((size_t)TILES_TOTAL * KV_TILE_BYTES)  // 17,301,504

typedef float f32x4 __attribute__((ext_vector_type(4)));
typedef short s16x8 __attribute__((ext_vector_type(8)));
typedef int   i32x4 __attribute__((ext_vector_type(4)));

static __device__ __forceinline__ int cvtpk(float lo, float hi) {
  int r;
  asm("v_cvt_pk_bf16_f32 %0, %1, %2" : "=v"(r) : "v"(lo), "v"(hi));
  return r;
}
static __device__ __forceinline__ s16x8 frag4(int a, int b, int c, int d) {
  i32x4 t = {a, b, c, d};
  return __builtin_bit_cast(s16x8, t);
}
static __device__ __forceinline__ float bf2f(unsigned int b) {
  return __uint_as_float(b << 16);
}

// ---------------------------------------------------------------------------
// Prepack: K/V f32 -> bf16 in the exact MFMA-fragment image order.
// (Proven R5-R12 kernel, unchanged.)
// ---------------------------------------------------------------------------
__global__ __launch_bounds__(256) void mt_prepack(
    const float* __restrict__ Kc, const float* __restrict__ Vc,
    const float* __restrict__ knew, const float* __restrict__ vnew,
    unsigned char* __restrict__ kv)
{
  const int t = blockIdx.x;
  const int t32 = t * KVB;
  const float* Kb = (t32 < S_CACHE) ? Kc + (size_t)t32 * D
                                    : knew + (size_t)(t32 - S_CACHE) * D;
  const float* Vb = (t32 < S_CACHE) ? Vc + (size_t)t32 * D
                                    : vnew + (size_t)(t32 - S_CACHE) * D;
  unsigned char* outb = kv + (size_t)t * KV_TILE_BYTES;
#pragma unroll
  for (int rep = 0; rep < 4; ++rep) {
    const int id = rep * 256 + threadIdx.x;
    const int chunk = id >> 6;   // uniform per wave
    const int l  = id & 63;
    const int g  = l >> 4, qq = l & 15;
    i32x4 outv;
    if (chunk < 8) {
      const int h = chunk >> 2, c = chunk & 3;
      const int krow = 8 * (qq >> 2) + (qq & 3) + 4 * h;
      const float* src = Kb + (size_t)krow * D + 32 * c + 8 * g;
      f32x4 x0 = *(const f32x4*)src;
      f32x4 x1 = *(const f32x4*)(src + 4);
      outv = i32x4{cvtpk(x0[0], x0[1]), cvtpk(x0[2], x0[3]),
                   cvtpk(x1[0], x1[1]), cvtpk(x1[2], x1[3])};
    } else {
      const int dt = chunk - 8;
      float v[8];
#pragma unroll
      for (int i = 0; i < 8; ++i)
        v[i] = Vb[(size_t)(8 * g + i) * D + 16 * dt + qq];
      outv = i32x4{cvtpk(v[0], v[1]), cvtpk(v[2], v[3]),
                   cvtpk(v[4], v[5]), cvtpk(v[6], v[7])};
    }
    *(i32x4*)(outb + (size_t)chunk * 1024 + l * 16) = outv;
  }
}

// ---------------------------------------------------------------------------
// Main: SINGLE-WAVE blocks (64 thr), fully independent -- no LDS, no
// barriers. BISECT vs R13: ONLY change is __launch_bounds__(64,2) (VGPR cap
// 256, vs R13's (64,4) cap-128 squeeze on a ~190-VGPR body -- the suspected
// NaN source; R2 precedent shows this knob forcing pathological allocation).
// grid = 32 qgroups x KSPLIT waves. XCD co-location: n -> xcd=n&7,
// qg=(n>>3)&31, s=xcd+8*(n>>8) (bijective; all split-s readers on XCD s%8).
// Per tile: 8x dwordx4 V loads + 8x K prefetch(t+1) into VGPRs from the
// prepacked wave-linear image -> 32 MFMA. R12-proven numerics verbatim.
// ---------------------------------------------------------------------------
template <int KSPLIT>
__global__ __launch_bounds__(64, 2) void mt_attn_main(
    const float* __restrict__ qp, const unsigned char* __restrict__ kv,
    unsigned char* __restrict__ ws)
{
  constexpr int TILES = TILES_TOTAL / KSPLIT;
  static_assert(TILES * KSPLIT == TILES_TOTAL, "KSPLIT must divide 1056");
  static_assert((KSPLIT & 7) == 0, "KSPLIT must be a multiple of 8");

  const int lane = threadIdx.x & 63;
  const int g    = lane >> 4;
  const int qq   = lane & 15;

  const int n    = blockIdx.x;
  const int s    = (n & 7) + 8 * (n >> 8);   // split, pinned to XCD s%8
  const int qg32 = (n >> 3) & 31;            // 32-q group
  const int t_st = s * TILES;

  // ---- Q fragments (B-operand): lane holds Q[q][32c+8g+i], scaled ----
  const float QSCALE = 0.0883883476483184f * 1.4426950408889634f;  // 1/sqrt(128)*log2(e)
  s16x8 qf[2][4];
#pragma unroll
  for (int u = 0; u < 2; ++u) {
    const float* qrow = qp + (size_t)(qg32 * 32 + u * 16 + qq) * D + 8 * g;
#pragma unroll
    for (int c = 0; c < 4; ++c) {
      f32x4 x0 = *(const f32x4*)(qrow + 32 * c);
      f32x4 x1 = *(const f32x4*)(qrow + 32 * c + 4);
      qf[u][c] = frag4(cvtpk(x0[0] * QSCALE, x0[1] * QSCALE),
                       cvtpk(x0[2] * QSCALE, x0[3] * QSCALE),
                       cvtpk(x1[0] * QSCALE, x1[1] * QSCALE),
                       cvtpk(x1[2] * QSCALE, x1[3] * QSCALE));
    }
  }

  f32x4 oacc[2][8];
#pragma unroll
  for (int u = 0; u < 2; ++u)
#pragma unroll
    for (int dt = 0; dt < 8; ++dt) {
      f32x4 z = {0.f, 0.f, 0.f, 0.f};
      oacc[u][dt] = z;
    }
  float mrun[2] = {-1e30f, -1e30f};
  float lrun[2] = {0.f, 0.f};

  // wave-local fragment base: chunk c of tile t at +t*16K + c*1024 + lane*16
  const unsigned char* kvb = kv + (size_t)t_st * KV_TILE_BYTES + lane * 16;

  i32x4 kk[2][8];  // K fragments, double-buffered (t&1 static under unroll)
  i32x4 vv[8];     // V fragments, per-tile

  // preload K(0)
#pragma unroll
  for (int c = 0; c < 8; ++c)
    kk[0][c] = *(const i32x4*)(kvb + c * 1024);

#pragma unroll
  for (int t = 0; t < TILES; ++t) {
    const unsigned char* tb = kvb + (size_t)t * KV_TILE_BYTES;

    // issue V(t) loads; consumed after QK^T+softmax (latency hidden)
#pragma unroll
    for (int c = 0; c < 8; ++c)
      vv[c] = *(const i32x4*)(tb + 8192 + c * 1024);

    // ---- QK^T (swapped): lane(g,qq) -> scores for q=qq, keys 8g+nn ----
    f32x4 sc[2][2];
#pragma unroll
    for (int u = 0; u < 2; ++u)
#pragma unroll
      for (int h = 0; h < 2; ++h) {
        f32x4 z = {0.f, 0.f, 0.f, 0.f};
        sc[u][h] = z;
      }
#pragma unroll
    for (int h = 0; h < 2; ++h)
#pragma unroll
      for (int c = 0; c < 4; ++c) {
        s16x8 kf = __builtin_bit_cast(s16x8, kk[t & 1][h * 4 + c]);
        sc[0][h] = __builtin_amdgcn_mfma_f32_16x16x32_bf16(kf, qf[0][c], sc[0][h], 0, 0, 0);
        sc[1][h] = __builtin_amdgcn_mfma_f32_16x16x32_bf16(kf, qf[1][c], sc[1][h], 0, 0, 0);
      }

    // prefetch K(t+1) into the other buffer
    if (t + 1 < TILES) {
#pragma unroll
      for (int c = 0; c < 8; ++c)
        kk[(t + 1) & 1][c] = *(const i32x4*)(tb + KV_TILE_BYTES + c * 1024);
    }

    // ---- softmax (proven: defer-max, base-2, lane-local rows) ----
    const int t32 = (t_st + t) * KVB;
    s16x8 pf[2];
#pragma unroll
    for (int u = 0; u < 2; ++u) {
      float sv[8];
#pragma unroll
      for (int h = 0; h < 2; ++h)
#pragma unroll
        for (int r = 0; r < 4; ++r)
          sv[4 * h + r] = sc[u][h][r];
      if (t32 >= S_CACHE) {  // causal mask (wave-uniform branch per tile)
        const int qglob = qg32 * 32 + u * 16 + qq;
#pragma unroll
        for (int nn = 0; nn < 8; ++nn) {
          const int key = t32 + 8 * g + nn;
          if (key - S_CACHE > qglob) sv[nn] = -1e30f;
        }
      }
      float vmax = fmaxf(fmaxf(fmaxf(sv[0], sv[1]), fmaxf(sv[2], sv[3])),
                         fmaxf(fmaxf(sv[4], sv[5]), fmaxf(sv[6], sv[7])));
      vmax = fmaxf(vmax, __shfl_xor(vmax, 16, 64));
      vmax = fmaxf(vmax, __shfl_xor(vmax, 32, 64));
      if (!__all(vmax <= mrun[u] + 8.f)) {  // defer-max
        const float mnew = fmaxf(mrun[u], vmax);
        const float corr = exp2f(mrun[u] - mnew);
        lrun[u] *= corr;
#pragma unroll
        for (int dt = 0; dt < 8; ++dt) oacc[u][dt] *= corr;
        mrun[u] = mnew;
      }
      float p[8], rs = 0.f;
#pragma unroll
      for (int nn = 0; nn < 8; ++nn) {
        p[nn] = exp2f(sv[nn] - mrun[u]);
        rs += p[nn];
      }
      lrun[u] += rs;  // per-lane partial; butterfly in epilogue
      pf[u] = frag4(cvtpk(p[0], p[1]), cvtpk(p[2], p[3]),
                    cvtpk(p[4], p[5]), cvtpk(p[6], p[7]));
    }

    // ---- PV (swapped): O^T += V^T @ P^T ----
#pragma unroll
    for (int dt = 0; dt < 8; ++dt) {
      s16x8 vf = __builtin_bit_cast(s16x8, vv[dt]);
      oacc[0][dt] = __builtin_amdgcn_mfma_f32_16x16x32_bf16(vf, pf[0], oacc[0][dt], 0, 0, 0);
      oacc[1][dt] = __builtin_amdgcn_mfma_f32_16x16x32_bf16(vf, pf[1], oacc[1][dt], 0, 0, 0);
    }
  }

  // ---- epilogue: cross-lane l reduction over the 4 g-groups ----
#pragma unroll
  for (int u = 0; u < 2; ++u) {
    lrun[u] += __shfl_xor(lrun[u], 16, 64);
    lrun[u] += __shfl_xor(lrun[u], 32, 64);
  }

  // ---- partials: packed u32 O^T (full-line stores) + dense m,l ----
  unsigned char* wsp = ws + KV_BYTES;
  unsigned int* pO = (unsigned int*)(wsp + (size_t)(qg32 * KSPLIT + s) * OBLK_BYTES);
  float* m_ws = (float*)(wsp + (size_t)32 * KSPLIT * OBLK_BYTES);
  float* l_ws = m_ws + (size_t)NQ * KSPLIT;
#pragma unroll
  for (int u = 0; u < 2; ++u) {
#pragma unroll
    for (int dt = 0; dt < 8; ++dt)
#pragma unroll
      for (int r2 = 0; r2 < 2; ++r2)
        pO[(8 * dt + 2 * g + r2) * 32 + u * 16 + qq] =
            (unsigned int)cvtpk(oacc[u][dt][2 * r2], oacc[u][dt][2 * r2 + 1]);
    if (g == 0) {
      const int q = qg32 * 32 + u * 16 + qq;
      m_ws[(size_t)q * KSPLIT + s] = mrun[u];
      l_ws[(size_t)q * KSPLIT + s] = lrun[u];
    }
  }
}

// ---------------------------------------------------------------------------
// Combine (proven, with m). One thread per (q, dv), full unroll.
// ---------------------------------------------------------------------------
template <int S>
__global__ __launch_bounds__(256) void mt_attn_combine(
    const unsigned char* __restrict__ ws, float* __restrict__ out)
{
  const int t  = blockIdx.x * 256 + threadIdx.x;  // 131072 total
  const int ql = t & 31;
  const int dv = (t >> 5) & 127;
  const int qg = t >> 12;
  const int q  = qg * 32 + ql;

  const unsigned char* wsp = ws + KV_BYTES;
  const float* m_ws = (const float*)(wsp + (size_t)32 * S * OBLK_BYTES);
  const float* l_ws = m_ws + (size_t)NQ * S;
  const float* mrow = m_ws + (size_t)q * S;
  const float* lrow = l_ws + (size_t)q * S;

  float mg = -1e30f;
#pragma unroll
  for (int s4 = 0; s4 < S / 4; ++s4) {
    f32x4 m4 = *(const f32x4*)(mrow + 4 * s4);
    mg = fmaxf(mg, fmaxf(fmaxf(m4[0], m4[1]), fmaxf(m4[2], m4[3])));
  }
  float L = 0.f;
#pragma unroll
  for (int s4 = 0; s4 < S / 4; ++s4) {
    f32x4 m4 = *(const f32x4*)(mrow + 4 * s4);
    f32x4 l4 = *(const f32x4*)(lrow + 4 * s4);
    L += l4[0] * exp2f(m4[0] - mg) + l4[1] * exp2f(m4[1] - mg) +
         l4[2] * exp2f(m4[2] - mg) + l4[3] * exp2f(m4[3] - mg);
  }
  // packed-O read: dv -> (dt, g, r); word (8dt+2g+(r>>1))*32 + ql, half r&1
  const int dt = dv >> 4, g2 = (dv >> 2) & 3, r = dv & 3;
  const int word = (8 * dt + 2 * g2 + (r >> 1)) * 32 + ql;
  const int sh = (r & 1) * 16;
  const unsigned int* base =
      (const unsigned int*)(wsp + (size_t)qg * S * OBLK_BYTES) + word;
  float acc = 0.f;
#pragma unroll
  for (int s = 0; s < S; ++s) {
    const float wgt = exp2f(mrow[s] - mg);
    acc += wgt * bf2f((base[(size_t)s * (OBLK_BYTES / 4)] >> sh) & 0xffffu);
  }
  out[(size_t)q * D + dv] = acc / L;
}

extern "C" void kernel_launch(void* const* d_in, const int* in_sizes, int n_in,
                              void* d_out, int out_size, void* d_ws, size_t ws_size,
                              hipStream_t stream)
{
  const float* qp = (const float*)d_in[0];
  const float* kp = (const float*)d_in[1];
  const float* vp = (const float*)d_in[2];
  const float* Kc = (const float*)d_in[3];
  const float* Vc = (const float*)d_in[4];
  float* out = (float*)d_out;
  unsigned char* ws = (unsigned char*)d_ws;

  // ws: [0, KV_BYTES) prepacked KV | O partials (32*K*8KB) | m,l (2*NQ*K*4)
  static const int cands[] = {96, 48, 32};
  int ksplit = 32;
  for (int i = 0; i < 3; ++i) {
    size_t need = KV_BYTES + (size_t)cands[i] * (32 * OBLK_BYTES + 8 * NQ);
    if (need <= ws_size) { ksplit = cands[i]; break; }
  }

  mt_prepack<<<dim3(TILES_TOTAL), dim3(256), 0, stream>>>(Kc, Vc, kp, vp, ws);

  const dim3 cgrid((NQ * D) / 256), cblk(256);
  switch (ksplit) {
    case 96:
      mt_attn_main<96><<<dim3(32 * 96), dim3(64), 0, stream>>>(qp, ws, ws);
      mt_attn_combine<96><<<cgrid, cblk, 0, stream>>>(ws, out);
      break;
    case 48:
      mt_attn_main<48><<<dim3(32 * 48), dim3(64), 0, stream>>>(qp, ws, ws);
      mt_attn_combine<48><<<cgrid, cblk, 0, stream>>>(ws, out);
      break;
    default:
      mt_attn_main<32><<<dim3(32 * 32), dim3(64), 0, stream>>>(qp, ws, ws);
      mt_attn_combine<32><<<cgrid, cblk, 0, stream>>>(ws, out);
      break;
  }
}

// Round 15
// 54.102 us; speedup vs baseline: 1.3285x; 1.1565x over previous
//
#include <hip/hip_runtime.h>

#define S_CACHE 32768
#define NQ 1024
#define D 128
#define KVB 32
#define TILES_TOTAL 1056
#define OBLK_BYTES 8192     // per (qg32, split): O^T packed u32 [chunk][32 q]
#define KV_TILE_BYTES 16384 // prepacked K frags (8 KB) + V frags (8 KB)
#define KV_BYTES ((size_t)TILES_TOTAL * KV_TILE_BYTES)  // 17,301,504

typedef float f32x4 __attribute__((ext_vector_type(4)));
typedef short s16x8 __attribute__((ext_vector_type(8)));
typedef int   i32x4 __attribute__((ext_vector_type(4)));

static __device__ __forceinline__ int cvtpk(float lo, float hi) {
  int r;
  asm("v_cvt_pk_bf16_f32 %0, %1, %2" : "=v"(r) : "v"(lo), "v"(hi));
  return r;
}
static __device__ __forceinline__ s16x8 frag4(int a, int b, int c, int d) {
  i32x4 t = {a, b, c, d};
  return __builtin_bit_cast(s16x8, t);
}
static __device__ __forceinline__ float bf2f(unsigned int b) {
  return __uint_as_float(b << 16);
}

// ---------------------------------------------------------------------------
// Prepack: K/V f32 -> bf16 in the exact MFMA-fragment image order.
// (Proven R5-R14 kernel, unchanged.)
// ---------------------------------------------------------------------------
__global__ __launch_bounds__(256) void mt_prepack(
    const float* __restrict__ Kc, const float* __restrict__ Vc,
    const float* __restrict__ knew, const float* __restrict__ vnew,
    unsigned char* __restrict__ kv)
{
  const int t = blockIdx.x;
  const int t32 = t * KVB;
  const float* Kb = (t32 < S_CACHE) ? Kc + (size_t)t32 * D
                                    : knew + (size_t)(t32 - S_CACHE) * D;
  const float* Vb = (t32 < S_CACHE) ? Vc + (size_t)t32 * D
                                    : vnew + (size_t)(t32 - S_CACHE) * D;
  unsigned char* outb = kv + (size_t)t * KV_TILE_BYTES;
#pragma unroll
  for (int rep = 0; rep < 4; ++rep) {
    const int id = rep * 256 + threadIdx.x;
    const int chunk = id >> 6;   // uniform per wave
    const int l  = id & 63;
    const int g  = l >> 4, qq = l & 15;
    i32x4 outv;
    if (chunk < 8) {
      const int h = chunk >> 2, c = chunk & 3;
      const int krow = 8 * (qq >> 2) + (qq & 3) + 4 * h;
      const float* src = Kb + (size_t)krow * D + 32 * c + 8 * g;
      f32x4 x0 = *(const f32x4*)src;
      f32x4 x1 = *(const f32x4*)(src + 4);
      outv = i32x4{cvtpk(x0[0], x0[1]), cvtpk(x0[2], x0[3]),
                   cvtpk(x1[0], x1[1]), cvtpk(x1[2], x1[3])};
    } else {
      const int dt = chunk - 8;
      float v[8];
#pragma unroll
      for (int i = 0; i < 8; ++i)
        v[i] = Vb[(size_t)(8 * g + i) * D + 16 * dt + qq];
      outv = i32x4{cvtpk(v[0], v[1]), cvtpk(v[2], v[3]),
                   cvtpk(v[4], v[5]), cvtpk(v[6], v[7])};
    }
    *(i32x4*)(outb + (size_t)chunk * 1024 + l * 16) = outv;
  }
}

// ---------------------------------------------------------------------------
// Main: SINGLE-WAVE blocks (64 thr), fully independent (R14-proven structure,
// __launch_bounds__(64,2) -- NEVER (64,4): reg-squeeze NaN, R13).
// Changes vs R14: (a) KSPLIT 96->48 (22 tiles/wave: amortize prologue 2x,
// halve partial traffic); (b) K(t+1) prefetch at TOP of tile (after V(t) --
// vmcnt FIFO: waiting for the older group leaves the younger in flight, so
// every load now has a full-tile issue->use distance); (c) manual parity-pair
// loop (static buffer names, rule #20) instead of 22-deep full unroll.
// XCD co-location: n -> xcd=n&7, qg=(n>>3)&31, s=xcd+8*(n>>8) (bijective).
// ---------------------------------------------------------------------------
template <int KSPLIT>
__global__ __launch_bounds__(64, 2) void mt_attn_main(
    const float* __restrict__ qp, const unsigned char* __restrict__ kv,
    unsigned char* __restrict__ ws)
{
  constexpr int TILES = TILES_TOTAL / KSPLIT;
  static_assert(TILES * KSPLIT == TILES_TOTAL, "KSPLIT must divide 1056");
  static_assert((KSPLIT & 7) == 0, "KSPLIT must be a multiple of 8");
  static_assert((TILES & 1) == 0, "parity-pair loop needs even TILES");

  const int lane = threadIdx.x & 63;
  const int g    = lane >> 4;
  const int qq   = lane & 15;

  const int n    = blockIdx.x;
  const int s    = (n & 7) + 8 * (n >> 8);   // split, pinned to XCD s%8
  const int qg32 = (n >> 3) & 31;            // 32-q group
  const int t_st = s * TILES;

  // ---- Q fragments (B-operand): lane holds Q[q][32c+8g+i], scaled ----
  const float QSCALE = 0.0883883476483184f * 1.4426950408889634f;  // 1/sqrt(128)*log2(e)
  s16x8 qf[2][4];
#pragma unroll
  for (int u = 0; u < 2; ++u) {
    const float* qrow = qp + (size_t)(qg32 * 32 + u * 16 + qq) * D + 8 * g;
#pragma unroll
    for (int c = 0; c < 4; ++c) {
      f32x4 x0 = *(const f32x4*)(qrow + 32 * c);
      f32x4 x1 = *(const f32x4*)(qrow + 32 * c + 4);
      qf[u][c] = frag4(cvtpk(x0[0] * QSCALE, x0[1] * QSCALE),
                       cvtpk(x0[2] * QSCALE, x0[3] * QSCALE),
                       cvtpk(x1[0] * QSCALE, x1[1] * QSCALE),
                       cvtpk(x1[2] * QSCALE, x1[3] * QSCALE));
    }
  }

  f32x4 oacc[2][8];
#pragma unroll
  for (int u = 0; u < 2; ++u)
#pragma unroll
    for (int dt = 0; dt < 8; ++dt) {
      f32x4 z = {0.f, 0.f, 0.f, 0.f};
      oacc[u][dt] = z;
    }
  float mrun[2] = {-1e30f, -1e30f};
  float lrun[2] = {0.f, 0.f};

  // wave-local fragment base: chunk c of tile t at +t*16K + c*1024 + lane*16
  const unsigned char* kvb = kv + (size_t)t_st * KV_TILE_BYTES + lane * 16;

  i32x4 kkA[8], kkB[8];  // K fragments, named double-buffer (static indices)
  i32x4 vv[8];           // V fragments, per-tile

  // ---- one tile: uses curk; prefetches K(t+1) into nxtk at the top ----
  auto step = [&](int t, i32x4 (&curk)[8], i32x4 (&nxtk)[8]) {
    const unsigned char* tb = kvb + (size_t)t * KV_TILE_BYTES;

    // V(t) first, then K(t+1): FIFO order => waiting on V(t)/K(t) never
    // drains the younger prefetch group.
#pragma unroll
    for (int c = 0; c < 8; ++c)
      vv[c] = *(const i32x4*)(tb + 8192 + c * 1024);
    if (t + 1 < TILES) {
#pragma unroll
      for (int c = 0; c < 8; ++c)
        nxtk[c] = *(const i32x4*)(tb + KV_TILE_BYTES + c * 1024);
    }

    // ---- QK^T (swapped): lane(g,qq) -> scores for q=qq, keys 8g+nn ----
    f32x4 sc[2][2];
#pragma unroll
    for (int u = 0; u < 2; ++u)
#pragma unroll
      for (int h = 0; h < 2; ++h) {
        f32x4 z = {0.f, 0.f, 0.f, 0.f};
        sc[u][h] = z;
      }
#pragma unroll
    for (int h = 0; h < 2; ++h)
#pragma unroll
      for (int c = 0; c < 4; ++c) {
        s16x8 kf = __builtin_bit_cast(s16x8, curk[h * 4 + c]);
        sc[0][h] = __builtin_amdgcn_mfma_f32_16x16x32_bf16(kf, qf[0][c], sc[0][h], 0, 0, 0);
        sc[1][h] = __builtin_amdgcn_mfma_f32_16x16x32_bf16(kf, qf[1][c], sc[1][h], 0, 0, 0);
      }

    // ---- softmax (proven: defer-max, base-2, lane-local rows) ----
    const int t32 = (t_st + t) * KVB;
    s16x8 pf[2];
#pragma unroll
    for (int u = 0; u < 2; ++u) {
      float sv[8];
#pragma unroll
      for (int h = 0; h < 2; ++h)
#pragma unroll
        for (int r = 0; r < 4; ++r)
          sv[4 * h + r] = sc[u][h][r];
      if (t32 >= S_CACHE) {  // causal mask (wave-uniform branch per tile)
        const int qglob = qg32 * 32 + u * 16 + qq;
#pragma unroll
        for (int nn = 0; nn < 8; ++nn) {
          const int key = t32 + 8 * g + nn;
          if (key - S_CACHE > qglob) sv[nn] = -1e30f;
        }
      }
      float vmax = fmaxf(fmaxf(fmaxf(sv[0], sv[1]), fmaxf(sv[2], sv[3])),
                         fmaxf(fmaxf(sv[4], sv[5]), fmaxf(sv[6], sv[7])));
      vmax = fmaxf(vmax, __shfl_xor(vmax, 16, 64));
      vmax = fmaxf(vmax, __shfl_xor(vmax, 32, 64));
      if (!__all(vmax <= mrun[u] + 8.f)) {  // defer-max
        const float mnew = fmaxf(mrun[u], vmax);
        const float corr = exp2f(mrun[u] - mnew);
        lrun[u] *= corr;
#pragma unroll
        for (int dt = 0; dt < 8; ++dt) oacc[u][dt] *= corr;
        mrun[u] = mnew;
      }
      float p[8], rs = 0.f;
#pragma unroll
      for (int nn = 0; nn < 8; ++nn) {
        p[nn] = exp2f(sv[nn] - mrun[u]);
        rs += p[nn];
      }
      lrun[u] += rs;  // per-lane partial; butterfly in epilogue
      pf[u] = frag4(cvtpk(p[0], p[1]), cvtpk(p[2], p[3]),
                    cvtpk(p[4], p[5]), cvtpk(p[6], p[7]));
    }

    // ---- PV (swapped): O^T += V^T @ P^T ----
#pragma unroll
    for (int dt = 0; dt < 8; ++dt) {
      s16x8 vf = __builtin_bit_cast(s16x8, vv[dt]);
      oacc[0][dt] = __builtin_amdgcn_mfma_f32_16x16x32_bf16(vf, pf[0], oacc[0][dt], 0, 0, 0);
      oacc[1][dt] = __builtin_amdgcn_mfma_f32_16x16x32_bf16(vf, pf[1], oacc[1][dt], 0, 0, 0);
    }
  };

  // preload K(0) into A
#pragma unroll
  for (int c = 0; c < 8; ++c)
    kkA[c] = *(const i32x4*)(kvb + c * 1024);

  for (int tp = 0; tp < TILES / 2; ++tp) {
    step(2 * tp,     kkA, kkB);
    step(2 * tp + 1, kkB, kkA);
  }

  // ---- epilogue: cross-lane l reduction over the 4 g-groups ----
#pragma unroll
  for (int u = 0; u < 2; ++u) {
    lrun[u] += __shfl_xor(lrun[u], 16, 64);
    lrun[u] += __shfl_xor(lrun[u], 32, 64);
  }

  // ---- partials: packed u32 O^T (full-line stores) + dense m,l ----
  unsigned char* wsp = ws + KV_BYTES;
  unsigned int* pO = (unsigned int*)(wsp + (size_t)(qg32 * KSPLIT + s) * OBLK_BYTES);
  float* m_ws = (float*)(wsp + (size_t)32 * KSPLIT * OBLK_BYTES);
  float* l_ws = m_ws + (size_t)NQ * KSPLIT;
#pragma unroll
  for (int u = 0; u < 2; ++u) {
#pragma unroll
    for (int dt = 0; dt < 8; ++dt)
#pragma unroll
      for (int r2 = 0; r2 < 2; ++r2)
        pO[(8 * dt + 2 * g + r2) * 32 + u * 16 + qq] =
            (unsigned int)cvtpk(oacc[u][dt][2 * r2], oacc[u][dt][2 * r2 + 1]);
    if (g == 0) {
      const int q = qg32 * 32 + u * 16 + qq;
      m_ws[(size_t)q * KSPLIT + s] = mrun[u];
      l_ws[(size_t)q * KSPLIT + s] = lrun[u];
    }
  }
}

// ---------------------------------------------------------------------------
// Combine (proven, with m). One thread per (q, dv), full unroll.
// ---------------------------------------------------------------------------
template <int S>
__global__ __launch_bounds__(256) void mt_attn_combine(
    const unsigned char* __restrict__ ws, float* __restrict__ out)
{
  const int t  = blockIdx.x * 256 + threadIdx.x;  // 131072 total
  const int ql = t & 31;
  const int dv = (t >> 5) & 127;
  const int qg = t >> 12;
  const int q  = qg * 32 + ql;

  const unsigned char* wsp = ws + KV_BYTES;
  const float* m_ws = (const float*)(wsp + (size_t)32 * S * OBLK_BYTES);
  const float* l_ws = m_ws + (size_t)NQ * S;
  const float* mrow = m_ws + (size_t)q * S;
  const float* lrow = l_ws + (size_t)q * S;

  float mg = -1e30f;
#pragma unroll
  for (int s4 = 0; s4 < S / 4; ++s4) {
    f32x4 m4 = *(const f32x4*)(mrow + 4 * s4);
    mg = fmaxf(mg, fmaxf(fmaxf(m4[0], m4[1]), fmaxf(m4[2], m4[3])));
  }
  float L = 0.f;
#pragma unroll
  for (int s4 = 0; s4 < S / 4; ++s4) {
    f32x4 m4 = *(const f32x4*)(mrow + 4 * s4);
    f32x4 l4 = *(const f32x4*)(lrow + 4 * s4);
    L += l4[0] * exp2f(m4[0] - mg) + l4[1] * exp2f(m4[1] - mg) +
         l4[2] * exp2f(m4[2] - mg) + l4[3] * exp2f(m4[3] - mg);
  }
  // packed-O read: dv -> (dt, g, r); word (8dt+2g+(r>>1))*32 + ql, half r&1
  const int dt = dv >> 4, g2 = (dv >> 2) & 3, r = dv & 3;
  const int word = (8 * dt + 2 * g2 + (r >> 1)) * 32 + ql;
  const int sh = (r & 1) * 16;
  const unsigned int* base =
      (const unsigned int*)(wsp + (size_t)qg * S * OBLK_BYTES) + word;
  float acc = 0.f;
#pragma unroll
  for (int s = 0; s < S; ++s) {
    const float wgt = exp2f(mrow[s] - mg);
    acc += wgt * bf2f((base[(size_t)s * (OBLK_BYTES / 4)] >> sh) & 0xffffu);
  }
  out[(size_t)q * D + dv] = acc / L;
}

extern "C" void kernel_launch(void* const* d_in, const int* in_sizes, int n_in,
                              void* d_out, int out_size, void* d_ws, size_t ws_size,
                              hipStream_t stream)
{
  const float* qp = (const float*)d_in[0];
  const float* kp = (const float*)d_in[1];
  const float* vp = (const float*)d_in[2];
  const float* Kc = (const float*)d_in[3];
  const float* Vc = (const float*)d_in[4];
  float* out = (float*)d_out;
  unsigned char* ws = (unsigned char*)d_ws;

  // ws: [0, KV_BYTES) prepacked KV | O partials (32*K*8KB) | m,l (2*NQ*K*4)
  static const int cands[] = {48, 24, 16, 8};
  int ksplit = 8;
  for (int i = 0; i < 4; ++i) {
    size_t need = KV_BYTES + (size_t)cands[i] * (32 * OBLK_BYTES + 8 * NQ);
    if (need <= ws_size) { ksplit = cands[i]; break; }
  }

  mt_prepack<<<dim3(TILES_TOTAL), dim3(256), 0, stream>>>(Kc, Vc, kp, vp, ws);

  const dim3 cgrid((NQ * D) / 256), cblk(256);
  switch (ksplit) {
    case 48:
      mt_attn_main<48><<<dim3(32 * 48), dim3(64), 0, stream>>>(qp, ws, ws);
      mt_attn_combine<48><<<cgrid, cblk, 0, stream>>>(ws, out);
      break;
    case 24:
      mt_attn_main<24><<<dim3(32 * 24), dim3(64), 0, stream>>>(qp, ws, ws);
      mt_attn_combine<24><<<cgrid, cblk, 0, stream>>>(ws, out);
      break;
    case 16:
      mt_attn_main<16><<<dim3(32 * 16), dim3(64), 0, stream>>>(qp, ws, ws);
      mt_attn_combine<16><<<cgrid, cblk, 0, stream>>>(ws, out);
      break;
    default:
      mt_attn_main<8><<<dim3(32 * 8), dim3(64), 0, stream>>>(qp, ws, ws);
      mt_attn_combine<8><<<cgrid, cblk, 0, stream>>>(ws, out);
      break;
  }
}